// Round 12
// baseline (542.409 us; speedup 1.0000x reference)
//
#include <hip/hip_runtime.h>
#include <cstddef>

#define T_ 1024
#define B_ 128
#define F_ 243
#define H_ 20
#define G_ 60   // 3*H
#define R_ 512  // B*POOL
#define P_ 8    // xg prefetch depth in k2 (also the e-store shift)
#define FP_ 256 // padded F for Wt (f-major transposed W_ih)
#define HS_ 244 // h_seq row stride: 244 floats = 976 B = 61*16 -> 16-B aligned rows
#define XS_ 80  // xg4 row stride: 20 j-slots x 4 (r,z,n,pad) floats

__device__ __forceinline__ float rdlane(float v, int l) {
  return __int_as_float(__builtin_amdgcn_readlane(__float_as_int(v), l));
}
#define RCP(x) __builtin_amdgcn_rcpf(x)
#if __has_builtin(__builtin_amdgcn_exp2f)
#define EXP2(x) __builtin_amdgcn_exp2f(x)
#else
#define EXP2(x) __expf((x) * 0.6931471805599453f)
#endif
#define NL2E_ -1.4426950408889634f   // -log2(e)
#define L2E2_ 2.8853900817779268f    // 2*log2(e)

// ---------------- K1a: streaming max-pool(4): feats -> h_seq (b-major, stride 244) -------
// Fully contiguous 972-B reads/writes, no LDS, no barriers (validated r7-r11).
// Blocks 0..59 additionally build Wt[256][60] (f-major transpose of W_ih,
// rows f>=243 zero); k1b launches after k1a so Wt is complete when consumed.
__global__ __launch_bounds__(256) void k1a_pool(
    const float* __restrict__ feats, float* __restrict__ h_seq,
    const float* __restrict__ W_ih, float* __restrict__ Wt)
{
  const int bid = blockIdx.x;           // 16384 = 1024 t x 16 b-groups
  if (bid < 60) {                       // folded k0: 60*256 >= FP_*G_
    const int i = bid * 256 + threadIdx.x;
    if (i < FP_ * G_) {
      const int f = i / G_, g = i - f * G_;
      Wt[(size_t)f * G_ + g] = (f < F_) ? W_ih[(size_t)g * F_ + f] : 0.f;
    }
  }
  const int t = bid & (T_ - 1);
  const int b0 = (bid >> 10) << 3;      // 8 batch rows per block
  const int col = threadIdx.x;
  if (col < F_) {
    #pragma unroll
    for (int bb = 0; bb < 8; ++bb) {
      const float* p =
          feats + ((size_t)t * R_ + (size_t)(b0 + bb) * 4) * F_ + col;
      const float v =
          fmaxf(fmaxf(p[0], p[F_]), fmaxf(p[2 * F_], p[3 * F_]));
      h_seq[((size_t)(b0 + bb) * T_ + t) * HS_ + col] = v;
    }
  }
}

// ---------------- K1b: GEMM  xg4 = h_seq @ W_ih^T + b_ih  (NO A-tile; r9-r11 core) -------
// A read directly from global (16 lanes of a rg-group load the SAME float4;
// coalescer collapses, L1-resident), consumed immediately -> no spills.
// Only Ws (15 KB/chunk) in LDS. NEW: output layout [b][t][j][4] = (r,z,n,pad)
// per hidden j, so k2 reads ONE dwordx4 per step. Each thread's 4 gates are
// gate-contiguous (same plane c = gc4/20, j = gc4-20c + q) -> 4 dword scatter
// in the epilogue (write-combined, off critical path).
__global__ __launch_bounds__(256) void k1b_gemm(
    const float* __restrict__ h_seq, const float* __restrict__ Wt,
    const float* __restrict__ b_ih, float* __restrict__ xg4)
{
  __shared__ __align__(16) float Ws[64 * 60];    // 15 KB, f-major chunk
  const int bid = blockIdx.x;
  const int b = bid >> 4;
  const int t0 = (bid & 15) << 6;          // 16 t-chunks of 64 rows
  const int tid = threadIdx.x;
  const int rg = tid >> 4;                 // 0..15 -> rows rg*4..rg*4+3
  const int gcol = tid & 15;               // 0..15 -> gates gcol*4..+3
  const int gc4 = (gcol < 15) ? gcol * 4 : 56;   // clamp col 15 (dup of 14)
  const float* hsb = h_seq + ((size_t)b * T_ + t0) * HS_;

  float acc[4][4];
  #pragma unroll
  for (int i = 0; i < 4; ++i)
    #pragma unroll
    for (int j = 0; j < 4; ++j) acc[i][j] = 0.f;

  for (int c = 0; c < 4; ++c) {            // f-chunks of 64
    const int FC = c * 64;
    __syncthreads();                       // Ws readers of chunk c-1 done
    for (int j = tid; j < 64 * 60; j += 256)
      Ws[j] = Wt[(size_t)FC * G_ + j];
    __syncthreads();
    #pragma unroll
    for (int fj = 0; fj < 16; ++fj) {
      const float* wp = &Ws[(fj * 4) * 60 + gc4];
      const float4 w0 = *(const float4*)(wp);
      const float4 w1 = *(const float4*)(wp + 60);
      const float4 w2 = *(const float4*)(wp + 120);
      const float4 w3 = *(const float4*)(wp + 180);
      #pragma unroll
      for (int i = 0; i < 4; ++i) {
        const int row = (rg << 2) + i;
        const float4 a4 =
            *(const float4*)&hsb[(size_t)row * HS_ + FC + fj * 4];
        acc[i][0] = fmaf(a4.x, w0.x, fmaf(a4.y, w1.x, fmaf(a4.z, w2.x, fmaf(a4.w, w3.x, acc[i][0]))));
        acc[i][1] = fmaf(a4.x, w0.y, fmaf(a4.y, w1.y, fmaf(a4.z, w2.y, fmaf(a4.w, w3.y, acc[i][1]))));
        acc[i][2] = fmaf(a4.x, w0.z, fmaf(a4.y, w1.z, fmaf(a4.z, w2.z, fmaf(a4.w, w3.z, acc[i][2]))));
        acc[i][3] = fmaf(a4.x, w0.w, fmaf(a4.y, w1.w, fmaf(a4.z, w2.w, fmaf(a4.w, w3.w, acc[i][3]))));
      }
    }
  }

  if (gcol < 15) {
    const float4 bi4 = *(const float4*)&b_ih[gc4];
    const int cpl = gc4 / 20;              // plane: 0=r, 1=z, 2=n (uniform per thread)
    const int jb = gc4 - cpl * 20;         // base hidden index
    #pragma unroll
    for (int i = 0; i < 4; ++i) {
      const int row = (rg << 2) + i;
      float* rp = &xg4[((size_t)b * T_ + t0 + row) * XS_ + cpl];
      rp[(jb + 0) * 4] = acc[i][0] + bi4.x;
      rp[(jb + 1) * 4] = acc[i][1] + bi4.y;
      rp[(jb + 2) * 4] = acc[i][2] + bi4.z;
      rp[(jb + 3) * 4] = acc[i][3] + bi4.w;
    }
  }
}

// ---------------- K2: recurrence only, zero cross-lane DS ops ----------------
// One wave per batch row; lane j<20 owns the gate triple (r_j,z_j,n_j); the
// shared e vector lives in SGPR pairs via v_readlane. NEW: per-step input is
// ONE aligned dwordx4 from xg4 (was 3 strided dwords) -> 8 outstanding loads
// max, constant 320-B pointer bump, no conservative-vmcnt serialization.
// e(t) goes into THIS block's own xg4 slab at packed offset (t-8)*20 (that
// row region's single load was issued >=8 steps earlier); t<8 -> ehead.
// NOTE: xg4 / e_store intentionally NOT __restrict__ (they alias).
__global__ __launch_bounds__(64) void k2_recur(
    const float* __restrict__ e0, const float* __restrict__ W_hh,
    const float* __restrict__ b_hh, const float* xg4,
    float* e_store, float* __restrict__ ehead)
{
  const int b = blockIdx.x;
  const int lane = threadIdx.x;
  const bool own = lane < H_;
  const int j0 = own ? lane : 0;

  float2 wr2[10], wz2[10], wn2[10];
  #pragma unroll
  for (int k = 0; k < 10; ++k) {
    wr2[k] = *(const float2*)&W_hh[j0 * H_ + 2 * k];
    wz2[k] = *(const float2*)&W_hh[(j0 + 20) * H_ + 2 * k];
    wn2[k] = *(const float2*)&W_hh[(j0 + 40) * H_ + 2 * k];
  }
  const float bhr = b_hh[j0], bhz = b_hh[j0 + 20], bhn = b_hh[j0 + 40];

  float e_own = e0[b * H_ + j0];
  float2 es2[10];
  #pragma unroll
  for (int k = 0; k < 10; ++k) {
    es2[k].x = rdlane(e_own, 2 * k);
    es2[k].y = rdlane(e_own, 2 * k + 1);
  }

  const float* xgb = xg4 + (size_t)b * T_ * XS_;
  float* xslab = e_store + (size_t)b * T_ * XS_;   // packed e at (t-8)*20
  float* ehb = ehead + b * (P_ * H_);

  float4 xv[P_];
  #pragma unroll
  for (int j = 0; j < P_; ++j)
    xv[j] = *(const float4*)&xgb[(size_t)j * XS_ + j0 * 4];

#define STEP(j, RELOAD)                                                    \
  {                                                                        \
    const int t = t0 + (j);                                                \
    const float xrv = xv[j].x, xzv = xv[j].y, xnv = xv[j].z;               \
    if (RELOAD) {                                                          \
      xv[j] = *(const float4*)&xgb[(size_t)(t + P_) * XS_ + j0 * 4];       \
    }                                                                      \
    float2 rA = make_float2(bhr, 0.f), rB = make_float2(0.f, 0.f);         \
    float2 zA = make_float2(bhz, 0.f), zB = make_float2(0.f, 0.f);         \
    float2 nA = make_float2(bhn, 0.f), nB = make_float2(0.f, 0.f);         \
    _Pragma("unroll")                                                      \
    for (int k = 0; k < 5; ++k) {                                          \
      rA = wr2[k] * es2[k] + rA;   rB = wr2[k + 5] * es2[k + 5] + rB;      \
      zA = wz2[k] * es2[k] + zA;   zB = wz2[k + 5] * es2[k + 5] + zB;      \
      nA = wn2[k] * es2[k] + nA;   nB = wn2[k + 5] * es2[k + 5] + nB;      \
    }                                                                      \
    const float hr = (rA.x + rB.x) + (rA.y + rB.y);                        \
    const float hz = (zA.x + zB.x) + (zA.y + zB.y);                        \
    const float hn = (nA.x + nB.x) + (nA.y + nB.y);                        \
    const float rg = RCP(1.f + EXP2((xrv + hr) * NL2E_));                  \
    const float zg = RCP(1.f + EXP2((xzv + hz) * NL2E_));                  \
    const float aa = fmaf(rg, hn, xnv);                                    \
    const float ng = 1.f - 2.f * RCP(EXP2(aa * L2E2_) + 1.f);              \
    const float enew = fmaf(zg, e_own - ng, ng);                           \
    if (own) {                                                             \
      float* dst = (t >= P_) ? (xslab + (size_t)(t - P_) * H_ + lane)      \
                             : (ehb + t * H_ + lane);                      \
      *dst = enew;                                                         \
    }                                                                      \
    e_own = enew;                                                          \
    _Pragma("unroll")                                                      \
    for (int k = 0; k < 10; ++k) {                                         \
      es2[k].x = rdlane(enew, 2 * k);                                      \
      es2[k].y = rdlane(enew, 2 * k + 1);                                  \
    }                                                                      \
  }

  for (int t0 = 0; t0 < T_ - P_; t0 += P_) {
    STEP(0, true) STEP(1, true) STEP(2, true) STEP(3, true)
    STEP(4, true) STEP(5, true) STEP(6, true) STEP(7, true)
  }
  {
    const int t0 = T_ - P_;
    STEP(0, false) STEP(1, false) STEP(2, false) STEP(3, false)
    STEP(4, false) STEP(5, false) STEP(6, false) STEP(7, false)
  }
#undef STEP
}

// ---------------- K4: decoder + squared-error (r9-r11 structure; new slab stride) --------
#define K4_ROWS 128
__global__ __launch_bounds__(256) void k4_decode(
    const float* __restrict__ W_dec, const float* __restrict__ b_dec,
    const float* __restrict__ h_seq, const float* __restrict__ e_store,
    const float* __restrict__ ehead, float* __restrict__ partials)
{
  __shared__ float elds[K4_ROWS * H_];   // 10 KB
  __shared__ float red[4];
  const int tid = threadIdx.x;
  const int f = tid;
  const bool act = f < F_;
  const int lane = tid & 63, wave = tid >> 6;
  const size_t r0 = (size_t)blockIdx.x * K4_ROWS;
  const int b = (int)(r0 >> 10);
  const int t0 = (int)(r0 & (T_ - 1));
  const float* xslab = e_store + (size_t)b * T_ * XS_;
  const float* ehb = ehead + b * (P_ * H_);

  for (int i = tid; i < K4_ROWS * H_; i += 256) {
    const int trow = i / H_;
    const int c = i - trow * H_;
    const int t = t0 + trow;
    elds[i] = (t >= P_) ? xslab[(size_t)(t - P_) * H_ + c] : ehb[t * H_ + c];
  }

  float wd[H_];
  float bd = 0.f;
  if (act) {
    #pragma unroll
    for (int k = 0; k < H_; ++k) wd[k] = W_dec[f * H_ + k];
    bd = b_dec[f];
  }
  __syncthreads();

  float acc = 0.f;
  #pragma unroll 2
  for (int i = 0; i < K4_ROWS; ++i) {
    const float2* ep = (const float2*)&elds[i * H_];
    float d = bd;
    #pragma unroll
    for (int k = 0; k < 10; ++k) {
      const float2 e2 = ep[k];
      d = fmaf(wd[2 * k], e2.x, fmaf(wd[2 * k + 1], e2.y, d));
    }
    const float fo = fmaxf(d, 0.f);
    if (act) {
      const float h = h_seq[(r0 + i) * HS_ + f];
      const float df = fo - h;
      acc = fmaf(df, df, acc);
    }
  }

  #pragma unroll
  for (int m = 32; m >= 1; m >>= 1) acc += __shfl_xor(acc, m);
  if (lane == 0) red[wave] = acc;
  __syncthreads();
  if (tid == 0) partials[blockIdx.x] = red[0] + red[1] + red[2] + red[3];
}

// ---------------- K3: final deterministic reduction over 1024 partials ----------------
__global__ __launch_bounds__(64) void k3_reduce(
    const float* __restrict__ partials, float* __restrict__ out)
{
  const int lane = threadIdx.x;
  float a = 0.f;
  #pragma unroll
  for (int i = 0; i < 16; ++i) a += partials[i * 64 + lane];
  #pragma unroll
  for (int m = 32; m >= 1; m >>= 1) a += __shfl_xor(a, m);
  if (lane == 0) out[0] = a * (float)(1.0 / ((double)T_ * B_ * F_));
}

extern "C" void kernel_launch(void* const* d_in, const int* in_sizes, int n_in,
                              void* d_out, int out_size, void* d_ws, size_t ws_size,
                              hipStream_t stream) {
  const float* feats = (const float*)d_in[0];
  const float* e0    = (const float*)d_in[1];
  const float* W_ih  = (const float*)d_in[2];
  const float* W_hh  = (const float*)d_in[3];
  const float* b_ih  = (const float*)d_in[4];
  const float* b_hh  = (const float*)d_in[5];
  const float* W_dec = (const float*)d_in[6];
  const float* b_dec = (const float*)d_in[7];
  float* out = (float*)d_out;

  float* ws = (float*)d_ws;
  float* h_seq    = ws;                                    // B*T*HS_ floats (b-major, padded)
  float* xgates   = ws + (size_t)B_ * T_ * HS_;            // B*T*XS_ floats (b-major, [j][4])
  float* partials = xgates + (size_t)B_ * T_ * XS_;        // 1024 floats
  float* ehead    = partials + 1024;                       // B*8*H floats (e for t<8)
  float* Wt       = ehead + B_ * P_ * H_;                  // FP_*G_ floats

  hipLaunchKernelGGL(k1a_pool, dim3(T_ * (B_ / 8)), dim3(256), 0, stream,
                     feats, h_seq, W_ih, Wt);
  hipLaunchKernelGGL(k1b_gemm, dim3(B_ * 16), dim3(256), 0, stream,
                     h_seq, Wt, b_ih, xgates);
  hipLaunchKernelGGL(k2_recur, dim3(B_), dim3(64), 0, stream,
                     e0, W_hh, b_hh, xgates, xgates, ehead);
  hipLaunchKernelGGL(k4_decode, dim3((T_ * B_) / K4_ROWS), dim3(256), 0, stream,
                     W_dec, b_dec, h_seq, xgates, ehead, partials);
  hipLaunchKernelGGL(k3_reduce, dim3(1), dim3(64), 0, stream,
                     partials, out);
}

// Round 13
// 452.792 us; speedup vs baseline: 1.1979x; 1.1979x over previous
//
#include <hip/hip_runtime.h>
#include <cstddef>

#define T_ 1024
#define B_ 128
#define F_ 243
#define H_ 20
#define G_ 60   // 3*H
#define R_ 512  // B*POOL
#define P_ 8    // xg prefetch depth / e-group size in k2
#define FP_ 256 // padded F for Wt (f-major transposed W_ih)
#define HS_ 244 // h_seq row stride: 244 floats = 976 B -> 16-B aligned rows

__device__ __forceinline__ float rdlane(float v, int l) {
  return __int_as_float(__builtin_amdgcn_readlane(__float_as_int(v), l));
}
#define RCP(x) __builtin_amdgcn_rcpf(x)
#if __has_builtin(__builtin_amdgcn_exp2f)
#define EXP2(x) __builtin_amdgcn_exp2f(x)
#else
#define EXP2(x) __expf((x) * 0.6931471805599453f)
#endif
#define NL2E_ -1.4426950408889634f   // -log2(e)
#define L2E2_ 2.8853900817779268f    // 2*log2(e)

// ---------------- K1a: streaming max-pool(4): feats -> h_seq (b-major, stride 244) -------
// Fully contiguous 972-B reads/writes, no LDS, no barriers (validated r7-r12).
// Blocks 0..59 additionally build Wt[256][60] (f-major transpose of W_ih,
// rows f>=243 zero); k1b launches after k1a so Wt is complete when consumed.
__global__ __launch_bounds__(256) void k1a_pool(
    const float* __restrict__ feats, float* __restrict__ h_seq,
    const float* __restrict__ W_ih, float* __restrict__ Wt)
{
  const int bid = blockIdx.x;           // 16384 = 1024 t x 16 b-groups
  if (bid < 60) {                       // folded k0: 60*256 >= FP_*G_
    const int i = bid * 256 + threadIdx.x;
    if (i < FP_ * G_) {
      const int f = i / G_, g = i - f * G_;
      Wt[(size_t)f * G_ + g] = (f < F_) ? W_ih[(size_t)g * F_ + f] : 0.f;
    }
  }
  const int t = bid & (T_ - 1);
  const int b0 = (bid >> 10) << 3;      // 8 batch rows per block
  const int col = threadIdx.x;
  if (col < F_) {
    #pragma unroll
    for (int bb = 0; bb < 8; ++bb) {
      const float* p =
          feats + ((size_t)t * R_ + (size_t)(b0 + bb) * 4) * F_ + col;
      const float v =
          fmaxf(fmaxf(p[0], p[F_]), fmaxf(p[2 * F_], p[3 * F_]));
      h_seq[((size_t)(b0 + bb) * T_ + t) * HS_ + col] = v;
    }
  }
}

// ---------------- K1b: GEMM  xg = h_seq @ W_ih^T + b_ih  (r11 version, validated) --------
// A read directly from global (16 lanes of a rg-group load the SAME float4;
// coalescer collapses, L1-resident), consumed immediately -> no spills. Only
// Ws (15 KB/chunk) in LDS. 64-row blocks (grid 2048) so one block's Ws-stage
// barriers hide under other blocks' FMA phases. Output: [b][t][G] float4s.
__global__ __launch_bounds__(256) void k1b_gemm(
    const float* __restrict__ h_seq, const float* __restrict__ Wt,
    const float* __restrict__ b_ih, float* __restrict__ xg)
{
  __shared__ __align__(16) float Ws[64 * 60];    // 15 KB, f-major chunk
  const int bid = blockIdx.x;
  const int b = bid >> 4;
  const int t0 = (bid & 15) << 6;          // 16 t-chunks of 64 rows
  const int tid = threadIdx.x;
  const int rg = tid >> 4;                 // 0..15 -> rows rg*4..rg*4+3
  const int gcol = tid & 15;               // 0..15 -> gates gcol*4..+3
  const int gc4 = (gcol < 15) ? gcol * 4 : 56;   // clamp col 15 (dup of 14)
  const float* hsb = h_seq + ((size_t)b * T_ + t0) * HS_;

  float acc[4][4];
  #pragma unroll
  for (int i = 0; i < 4; ++i)
    #pragma unroll
    for (int j = 0; j < 4; ++j) acc[i][j] = 0.f;

  for (int c = 0; c < 4; ++c) {            // f-chunks of 64
    const int FC = c * 64;
    __syncthreads();                       // Ws readers of chunk c-1 done
    for (int j = tid; j < 64 * 60; j += 256)
      Ws[j] = Wt[(size_t)FC * G_ + j];
    __syncthreads();
    #pragma unroll
    for (int fj = 0; fj < 16; ++fj) {
      const float* wp = &Ws[(fj * 4) * 60 + gc4];
      const float4 w0 = *(const float4*)(wp);
      const float4 w1 = *(const float4*)(wp + 60);
      const float4 w2 = *(const float4*)(wp + 120);
      const float4 w3 = *(const float4*)(wp + 180);
      #pragma unroll
      for (int i = 0; i < 4; ++i) {
        const int row = (rg << 2) + i;
        const float4 a4 =
            *(const float4*)&hsb[(size_t)row * HS_ + FC + fj * 4];
        acc[i][0] = fmaf(a4.x, w0.x, fmaf(a4.y, w1.x, fmaf(a4.z, w2.x, fmaf(a4.w, w3.x, acc[i][0]))));
        acc[i][1] = fmaf(a4.x, w0.y, fmaf(a4.y, w1.y, fmaf(a4.z, w2.y, fmaf(a4.w, w3.y, acc[i][1]))));
        acc[i][2] = fmaf(a4.x, w0.z, fmaf(a4.y, w1.z, fmaf(a4.z, w2.z, fmaf(a4.w, w3.z, acc[i][2]))));
        acc[i][3] = fmaf(a4.x, w0.w, fmaf(a4.y, w1.w, fmaf(a4.z, w2.w, fmaf(a4.w, w3.w, acc[i][3]))));
      }
    }
  }

  if (gcol < 15) {
    const float4 bi4 = *(const float4*)&b_ih[gc4];
    #pragma unroll
    for (int i = 0; i < 4; ++i) {
      const int row = (rg << 2) + i;
      float4 o;
      o.x = acc[i][0] + bi4.x;  o.y = acc[i][1] + bi4.y;
      o.z = acc[i][2] + bi4.z;  o.w = acc[i][3] + bi4.w;
      *(float4*)&xg[((size_t)b * T_ + t0 + row) * G_ + gc4] = o;
    }
  }
}

// ---------------- K2: fused recurrence + decoder + loss ----------------
// 5 waves per block, one block per batch row. Wave 0 = the r10/r11-validated
// register recurrence (lane j<20 owns gate triple; e broadcast via readlane;
// 3 dword xg loads/step with depth-8 rotating prefetch). It publishes e(t)
// into ping-pong LDS ebuf[2][8][20] and barriers once per 8 steps (128
// barriers). Waves 1-4 (thread = decoder column f, W_dec row in regs) decode
// group g while the producer computes g+1; h_seq prefetched one group ahead.
// Consumer work (~370cy/group) hides fully under producer (~1200cy/group).
// Replaces the separate k4 kernel and removes all e_seq global traffic.
__global__ __launch_bounds__(320) void k2_fused(
    const float* __restrict__ e0, const float* __restrict__ W_hh,
    const float* __restrict__ b_hh, const float* __restrict__ xg,
    const float* __restrict__ h_seq, const float* __restrict__ W_dec,
    const float* __restrict__ b_dec, float* __restrict__ partials)
{
  __shared__ float ebuf[2][P_][H_];   // 1280 B ping-pong
  __shared__ float red[8];
  const int b = blockIdx.x;
  const int tid = threadIdx.x;
  const int lane = tid & 63;
  const int wave = tid >> 6;
  float acc = 0.f;   // producer wave leaves 0

  if (wave == 0) {
    // ---------------- producer: recurrence ----------------
    const bool own = lane < H_;
    const int j0 = own ? lane : 0;

    float2 wr2[10], wz2[10], wn2[10];
    #pragma unroll
    for (int k = 0; k < 10; ++k) {
      wr2[k] = *(const float2*)&W_hh[j0 * H_ + 2 * k];
      wz2[k] = *(const float2*)&W_hh[(j0 + 20) * H_ + 2 * k];
      wn2[k] = *(const float2*)&W_hh[(j0 + 40) * H_ + 2 * k];
    }
    const float bhr = b_hh[j0], bhz = b_hh[j0 + 20], bhn = b_hh[j0 + 40];

    float e_own = e0[b * H_ + j0];
    float2 es2[10];
    #pragma unroll
    for (int k = 0; k < 10; ++k) {
      es2[k].x = rdlane(e_own, 2 * k);
      es2[k].y = rdlane(e_own, 2 * k + 1);
    }

    const float* xgb = xg + (size_t)b * T_ * G_;
    float xr[P_], xz[P_], xn[P_];
    #pragma unroll
    for (int j = 0; j < P_; ++j) {
      xr[j] = xgb[(size_t)j * G_ + j0];
      xz[j] = xgb[(size_t)j * G_ + j0 + 20];
      xn[j] = xgb[(size_t)j * G_ + j0 + 40];
    }

#define STEP(j, RELOAD)                                                    \
    {                                                                      \
      const int t = t0 + (j);                                              \
      const float xrv = xr[j], xzv = xz[j], xnv = xn[j];                   \
      if (RELOAD) {                                                        \
        const float* xp = xgb + (size_t)(t + P_) * G_;                     \
        xr[j] = xp[j0]; xz[j] = xp[j0 + 20]; xn[j] = xp[j0 + 40];          \
      }                                                                    \
      float2 rA = make_float2(bhr, 0.f), rB = make_float2(0.f, 0.f);       \
      float2 zA = make_float2(bhz, 0.f), zB = make_float2(0.f, 0.f);       \
      float2 nA = make_float2(bhn, 0.f), nB = make_float2(0.f, 0.f);       \
      _Pragma("unroll")                                                    \
      for (int k = 0; k < 5; ++k) {                                        \
        rA = wr2[k] * es2[k] + rA;   rB = wr2[k + 5] * es2[k + 5] + rB;    \
        zA = wz2[k] * es2[k] + zA;   zB = wz2[k + 5] * es2[k + 5] + zB;    \
        nA = wn2[k] * es2[k] + nA;   nB = wn2[k + 5] * es2[k + 5] + nB;    \
      }                                                                    \
      const float hr = (rA.x + rB.x) + (rA.y + rB.y);                      \
      const float hz = (zA.x + zB.x) + (zA.y + zB.y);                      \
      const float hn = (nA.x + nB.x) + (nA.y + nB.y);                      \
      const float rg = RCP(1.f + EXP2((xrv + hr) * NL2E_));                \
      const float zg = RCP(1.f + EXP2((xzv + hz) * NL2E_));                \
      const float aa = fmaf(rg, hn, xnv);                                  \
      const float ng = 1.f - 2.f * RCP(EXP2(aa * L2E2_) + 1.f);            \
      const float enew = fmaf(zg, e_own - ng, ng);                         \
      if (own) ebuf[(t0 >> 3) & 1][j][lane] = enew;                        \
      e_own = enew;                                                        \
      _Pragma("unroll")                                                    \
      for (int k = 0; k < 10; ++k) {                                       \
        es2[k].x = rdlane(enew, 2 * k);                                    \
        es2[k].y = rdlane(enew, 2 * k + 1);                                \
      }                                                                    \
    }

    for (int t0 = 0; t0 < T_ - P_; t0 += P_) {
      STEP(0, true) STEP(1, true) STEP(2, true) STEP(3, true)
      STEP(4, true) STEP(5, true) STEP(6, true) STEP(7, true)
      __syncthreads();                 // publish group t0/8
    }
    {
      const int t0 = T_ - P_;
      STEP(0, false) STEP(1, false) STEP(2, false) STEP(3, false)
      STEP(4, false) STEP(5, false) STEP(6, false) STEP(7, false)
      __syncthreads();                 // publish last group
    }
#undef STEP
  } else {
    // ---------------- consumers: decoder + squared error ----------------
    const int ct = tid - 64;           // 0..255
    const bool act = ct < F_;
    const int f = act ? ct : 0;
    float wd[H_];
    #pragma unroll
    for (int k = 0; k < H_; ++k) wd[k] = W_dec[f * H_ + k];
    const float bd = b_dec[f];
    const float* hsb = h_seq + (size_t)b * T_ * HS_;

    float hcur[P_], hnxt[P_];
    #pragma unroll
    for (int j = 0; j < P_; ++j) hcur[j] = hsb[(size_t)j * HS_ + f];

    for (int g = 0; g < T_ / P_; ++g) {
      __syncthreads();                 // ebuf group g published
      if (g < T_ / P_ - 1) {
        #pragma unroll
        for (int j = 0; j < P_; ++j)
          hnxt[j] = hsb[(size_t)(P_ * (g + 1) + j) * HS_ + f];
      }
      const float* eb = &ebuf[g & 1][0][0];
      #pragma unroll
      for (int j = 0; j < P_; ++j) {
        const float2* ep = (const float2*)&eb[j * H_];
        float d = bd;
        #pragma unroll
        for (int k = 0; k < 10; ++k) {
          const float2 e2 = ep[k];
          d = fmaf(wd[2 * k], e2.x, fmaf(wd[2 * k + 1], e2.y, d));
        }
        const float fo = fmaxf(d, 0.f);
        const float df = fo - hcur[j];
        if (act) acc = fmaf(df, df, acc);
      }
      #pragma unroll
      for (int j = 0; j < P_; ++j) hcur[j] = hnxt[j];
    }
  }

  // deterministic block reduction (producer contributes 0)
  #pragma unroll
  for (int m = 32; m >= 1; m >>= 1) acc += __shfl_xor(acc, m);
  if (lane == 0) red[wave] = acc;
  __syncthreads();
  if (tid == 0)
    partials[b] = ((red[0] + red[1]) + (red[2] + red[3])) + red[4];
}

// ---------------- K3: final deterministic reduction over 128 partials ----------------
__global__ __launch_bounds__(64) void k3_reduce(
    const float* __restrict__ partials, float* __restrict__ out)
{
  const int lane = threadIdx.x;
  float a = partials[lane] + partials[lane + 64];
  #pragma unroll
  for (int m = 32; m >= 1; m >>= 1) a += __shfl_xor(a, m);
  if (lane == 0) out[0] = a * (float)(1.0 / ((double)T_ * B_ * F_));
}

extern "C" void kernel_launch(void* const* d_in, const int* in_sizes, int n_in,
                              void* d_out, int out_size, void* d_ws, size_t ws_size,
                              hipStream_t stream) {
  const float* feats = (const float*)d_in[0];
  const float* e0    = (const float*)d_in[1];
  const float* W_ih  = (const float*)d_in[2];
  const float* W_hh  = (const float*)d_in[3];
  const float* b_ih  = (const float*)d_in[4];
  const float* b_hh  = (const float*)d_in[5];
  const float* W_dec = (const float*)d_in[6];
  const float* b_dec = (const float*)d_in[7];
  float* out = (float*)d_out;

  float* ws = (float*)d_ws;
  float* h_seq    = ws;                                    // B*T*HS_ floats (b-major, padded)
  float* xgates   = ws + (size_t)B_ * T_ * HS_;            // B*T*G floats (b-major)
  float* partials = xgates + (size_t)B_ * T_ * G_;         // 128 floats
  float* Wt       = partials + 128;                        // FP_*G_ floats

  hipLaunchKernelGGL(k1a_pool, dim3(T_ * (B_ / 8)), dim3(256), 0, stream,
                     feats, h_seq, W_ih, Wt);
  hipLaunchKernelGGL(k1b_gemm, dim3(B_ * 16), dim3(256), 0, stream,
                     h_seq, Wt, b_ih, xgates);
  hipLaunchKernelGGL(k2_fused, dim3(B_), dim3(320), 0, stream,
                     e0, W_hh, b_hh, xgates, h_seq, W_dec, b_dec, partials);
  hipLaunchKernelGGL(k3_reduce, dim3(1), dim3(64), 0, stream,
                     partials, out);
}

// Round 14
// 445.487 us; speedup vs baseline: 1.2176x; 1.0164x over previous
//
#include <hip/hip_runtime.h>
#include <cstddef>

#define T_ 1024
#define B_ 128
#define F_ 243
#define H_ 20
#define G_ 60   // 3*H
#define R_ 512  // B*POOL
#define P_ 8    // xg prefetch depth / e-group size in k2
#define FP_ 256 // padded F for Wt (f-major transposed W_ih)
#define HS_ 244 // h_seq row stride: 244 floats = 976 B -> 16-B aligned rows

__device__ __forceinline__ float rdlane(float v, int l) {
  return __int_as_float(__builtin_amdgcn_readlane(__float_as_int(v), l));
}
#define RCP(x) __builtin_amdgcn_rcpf(x)
#if __has_builtin(__builtin_amdgcn_exp2f)
#define EXP2(x) __builtin_amdgcn_exp2f(x)
#else
#define EXP2(x) __expf((x) * 0.6931471805599453f)
#endif
#define NL2E_ -1.4426950408889634f   // -log2(e)
#define L2E2_ 2.8853900817779268f    // 2*log2(e)

// ---------------- K1a: streaming max-pool(4): feats -> h_seq (b-major, stride 244) -------
// Fully contiguous 972-B reads/writes, no LDS, no barriers (validated r7-r13).
// Blocks 0..59 additionally build Wt[256][60] (f-major transpose of W_ih,
// rows f>=243 zero); k1b launches after k1a so Wt is complete when consumed.
__global__ __launch_bounds__(256) void k1a_pool(
    const float* __restrict__ feats, float* __restrict__ h_seq,
    const float* __restrict__ W_ih, float* __restrict__ Wt)
{
  const int bid = blockIdx.x;           // 16384 = 1024 t x 16 b-groups
  if (bid < 60) {                       // folded k0: 60*256 >= FP_*G_
    const int i = bid * 256 + threadIdx.x;
    if (i < FP_ * G_) {
      const int f = i / G_, g = i - f * G_;
      Wt[(size_t)f * G_ + g] = (f < F_) ? W_ih[(size_t)g * F_ + f] : 0.f;
    }
  }
  const int t = bid & (T_ - 1);
  const int b0 = (bid >> 10) << 3;      // 8 batch rows per block
  const int col = threadIdx.x;
  if (col < F_) {
    #pragma unroll
    for (int bb = 0; bb < 8; ++bb) {
      const float* p =
          feats + ((size_t)t * R_ + (size_t)(b0 + bb) * 4) * F_ + col;
      const float v =
          fmaxf(fmaxf(p[0], p[F_]), fmaxf(p[2 * F_], p[3 * F_]));
      h_seq[((size_t)(b0 + bb) * T_ + t) * HS_ + col] = v;
    }
  }
}

// ---------------- K1b: GEMM  xg = h_seq @ W_ih^T + b_ih  (r11/r13 version, validated) ----
// A read directly from global (16 lanes of a rg-group load the SAME float4;
// coalescer collapses, L1-resident), consumed immediately -> no spills. Only
// Ws (15 KB/chunk) in LDS. 64-row blocks (grid 2048) so one block's Ws-stage
// barriers hide under other blocks' FMA phases. Output: [b][t][G] float4s.
__global__ __launch_bounds__(256) void k1b_gemm(
    const float* __restrict__ h_seq, const float* __restrict__ Wt,
    const float* __restrict__ b_ih, float* __restrict__ xg)
{
  __shared__ __align__(16) float Ws[64 * 60];    // 15 KB, f-major chunk
  const int bid = blockIdx.x;
  const int b = bid >> 4;
  const int t0 = (bid & 15) << 6;          // 16 t-chunks of 64 rows
  const int tid = threadIdx.x;
  const int rg = tid >> 4;                 // 0..15 -> rows rg*4..rg*4+3
  const int gcol = tid & 15;               // 0..15 -> gates gcol*4..+3
  const int gc4 = (gcol < 15) ? gcol * 4 : 56;   // clamp col 15 (dup of 14)
  const float* hsb = h_seq + ((size_t)b * T_ + t0) * HS_;

  float acc[4][4];
  #pragma unroll
  for (int i = 0; i < 4; ++i)
    #pragma unroll
    for (int j = 0; j < 4; ++j) acc[i][j] = 0.f;

  for (int c = 0; c < 4; ++c) {            // f-chunks of 64
    const int FC = c * 64;
    __syncthreads();                       // Ws readers of chunk c-1 done
    for (int j = tid; j < 64 * 60; j += 256)
      Ws[j] = Wt[(size_t)FC * G_ + j];
    __syncthreads();
    #pragma unroll
    for (int fj = 0; fj < 16; ++fj) {
      const float* wp = &Ws[(fj * 4) * 60 + gc4];
      const float4 w0 = *(const float4*)(wp);
      const float4 w1 = *(const float4*)(wp + 60);
      const float4 w2 = *(const float4*)(wp + 120);
      const float4 w3 = *(const float4*)(wp + 180);
      #pragma unroll
      for (int i = 0; i < 4; ++i) {
        const int row = (rg << 2) + i;
        const float4 a4 =
            *(const float4*)&hsb[(size_t)row * HS_ + FC + fj * 4];
        acc[i][0] = fmaf(a4.x, w0.x, fmaf(a4.y, w1.x, fmaf(a4.z, w2.x, fmaf(a4.w, w3.x, acc[i][0]))));
        acc[i][1] = fmaf(a4.x, w0.y, fmaf(a4.y, w1.y, fmaf(a4.z, w2.y, fmaf(a4.w, w3.y, acc[i][1]))));
        acc[i][2] = fmaf(a4.x, w0.z, fmaf(a4.y, w1.z, fmaf(a4.z, w2.z, fmaf(a4.w, w3.z, acc[i][2]))));
        acc[i][3] = fmaf(a4.x, w0.w, fmaf(a4.y, w1.w, fmaf(a4.z, w2.w, fmaf(a4.w, w3.w, acc[i][3]))));
      }
    }
  }

  if (gcol < 15) {
    const float4 bi4 = *(const float4*)&b_ih[gc4];
    #pragma unroll
    for (int i = 0; i < 4; ++i) {
      const int row = (rg << 2) + i;
      float4 o;
      o.x = acc[i][0] + bi4.x;  o.y = acc[i][1] + bi4.y;
      o.z = acc[i][2] + bi4.z;  o.w = acc[i][3] + bi4.w;
      *(float4*)&xg[((size_t)b * T_ + t0 + row) * G_ + gc4] = o;
    }
  }
}

// ---------------- K2: fused recurrence + decoder + loss ----------------
// Structure identical to r13 (452 us, validated). Producer chain cut: the
// exp2 base-conversion constants are folded into W_hh/b_hh at LOAD time
// (rows r,z scaled by -log2e; row n by 2*log2e) and into the prefetched
// x-gate values (off-chain muls in the RELOAD block). Per step this removes
// 3 muls + a reassociation from the serial chain (~14 cy of ~110).
__global__ __launch_bounds__(320) void k2_fused(
    const float* __restrict__ e0, const float* __restrict__ W_hh,
    const float* __restrict__ b_hh, const float* __restrict__ xg,
    const float* __restrict__ h_seq, const float* __restrict__ W_dec,
    const float* __restrict__ b_dec, float* __restrict__ partials)
{
  __shared__ float ebuf[2][P_][H_];   // 1280 B ping-pong
  __shared__ float red[8];
  const int b = blockIdx.x;
  const int tid = threadIdx.x;
  const int lane = tid & 63;
  const int wave = tid >> 6;
  float acc = 0.f;   // producer wave leaves 0

  if (wave == 0) {
    // ---------------- producer: recurrence ----------------
    const bool own = lane < H_;
    const int j0 = own ? lane : 0;

    float2 wr2[10], wz2[10], wn2[10];
    #pragma unroll
    for (int k = 0; k < 10; ++k) {
      const float2 a = *(const float2*)&W_hh[j0 * H_ + 2 * k];
      const float2 c = *(const float2*)&W_hh[(j0 + 20) * H_ + 2 * k];
      const float2 d = *(const float2*)&W_hh[(j0 + 40) * H_ + 2 * k];
      wr2[k] = make_float2(a.x * NL2E_, a.y * NL2E_);
      wz2[k] = make_float2(c.x * NL2E_, c.y * NL2E_);
      wn2[k] = make_float2(d.x * L2E2_, d.y * L2E2_);
    }
    const float bhr = b_hh[j0] * NL2E_;
    const float bhz = b_hh[j0 + 20] * NL2E_;
    const float bhn = b_hh[j0 + 40] * L2E2_;

    float e_own = e0[b * H_ + j0];
    float2 es2[10];
    #pragma unroll
    for (int k = 0; k < 10; ++k) {
      es2[k].x = rdlane(e_own, 2 * k);
      es2[k].y = rdlane(e_own, 2 * k + 1);
    }

    const float* xgb = xg + (size_t)b * T_ * G_;
    float xr[P_], xz[P_], xn[P_];
    #pragma unroll
    for (int j = 0; j < P_; ++j) {
      xr[j] = xgb[(size_t)j * G_ + j0] * NL2E_;
      xz[j] = xgb[(size_t)j * G_ + j0 + 20] * NL2E_;
      xn[j] = xgb[(size_t)j * G_ + j0 + 40] * L2E2_;
    }

#define STEP(j, RELOAD)                                                    \
    {                                                                      \
      const int t = t0 + (j);                                              \
      const float xrv = xr[j], xzv = xz[j], xnv = xn[j];                   \
      if (RELOAD) {                                                        \
        const float* xp = xgb + (size_t)(t + P_) * G_;                     \
        xr[j] = xp[j0] * NL2E_;                                            \
        xz[j] = xp[j0 + 20] * NL2E_;                                       \
        xn[j] = xp[j0 + 40] * L2E2_;                                       \
      }                                                                    \
      float2 rA = make_float2(bhr, 0.f), rB = make_float2(0.f, 0.f);       \
      float2 zA = make_float2(bhz, 0.f), zB = make_float2(0.f, 0.f);       \
      float2 nA = make_float2(bhn, 0.f), nB = make_float2(0.f, 0.f);       \
      _Pragma("unroll")                                                    \
      for (int k = 0; k < 5; ++k) {                                        \
        rA = wr2[k] * es2[k] + rA;   rB = wr2[k + 5] * es2[k + 5] + rB;    \
        zA = wz2[k] * es2[k] + zA;   zB = wz2[k + 5] * es2[k + 5] + zB;    \
        nA = wn2[k] * es2[k] + nA;   nB = wn2[k + 5] * es2[k + 5] + nB;    \
      }                                                                    \
      const float hr2 = (rA.x + rB.x) + (rA.y + rB.y);                     \
      const float hz2 = (zA.x + zB.x) + (zA.y + zB.y);                     \
      const float hn2 = (nA.x + nB.x) + (nA.y + nB.y);                     \
      const float rg = RCP(1.f + EXP2(xrv + hr2));                         \
      const float zg = RCP(1.f + EXP2(xzv + hz2));                         \
      const float aa2 = fmaf(rg, hn2, xnv);                                \
      const float ng = fmaf(-2.f, RCP(EXP2(aa2) + 1.f), 1.f);              \
      const float enew = fmaf(zg, e_own - ng, ng);                         \
      if (own) ebuf[(t0 >> 3) & 1][j][lane] = enew;                        \
      e_own = enew;                                                        \
      _Pragma("unroll")                                                    \
      for (int k = 0; k < 10; ++k) {                                       \
        es2[k].x = rdlane(enew, 2 * k);                                    \
        es2[k].y = rdlane(enew, 2 * k + 1);                                \
      }                                                                    \
    }

    for (int t0 = 0; t0 < T_ - P_; t0 += P_) {
      STEP(0, true) STEP(1, true) STEP(2, true) STEP(3, true)
      STEP(4, true) STEP(5, true) STEP(6, true) STEP(7, true)
      __syncthreads();                 // publish group t0/8
    }
    {
      const int t0 = T_ - P_;
      STEP(0, false) STEP(1, false) STEP(2, false) STEP(3, false)
      STEP(4, false) STEP(5, false) STEP(6, false) STEP(7, false)
      __syncthreads();                 // publish last group
    }
#undef STEP
  } else {
    // ---------------- consumers: decoder + squared error ----------------
    const int ct = tid - 64;           // 0..255
    const bool act = ct < F_;
    const int f = act ? ct : 0;
    float wd[H_];
    #pragma unroll
    for (int k = 0; k < H_; ++k) wd[k] = W_dec[f * H_ + k];
    const float bd = b_dec[f];
    const float* hsb = h_seq + (size_t)b * T_ * HS_;

    float hcur[P_], hnxt[P_];
    #pragma unroll
    for (int j = 0; j < P_; ++j) hcur[j] = hsb[(size_t)j * HS_ + f];

    for (int g = 0; g < T_ / P_; ++g) {
      __syncthreads();                 // ebuf group g published
      if (g < T_ / P_ - 1) {
        #pragma unroll
        for (int j = 0; j < P_; ++j)
          hnxt[j] = hsb[(size_t)(P_ * (g + 1) + j) * HS_ + f];
      }
      const float* eb = &ebuf[g & 1][0][0];
      #pragma unroll
      for (int j = 0; j < P_; ++j) {
        const float2* ep = (const float2*)&eb[j * H_];
        float d = bd;
        #pragma unroll
        for (int k = 0; k < 10; ++k) {
          const float2 e2 = ep[k];
          d = fmaf(wd[2 * k], e2.x, fmaf(wd[2 * k + 1], e2.y, d));
        }
        const float fo = fmaxf(d, 0.f);
        const float df = fo - hcur[j];
        if (act) acc = fmaf(df, df, acc);
      }
      #pragma unroll
      for (int j = 0; j < P_; ++j) hcur[j] = hnxt[j];
    }
  }

  // deterministic block reduction (producer contributes 0)
  #pragma unroll
  for (int m = 32; m >= 1; m >>= 1) acc += __shfl_xor(acc, m);
  if (lane == 0) red[wave] = acc;
  __syncthreads();
  if (tid == 0)
    partials[b] = ((red[0] + red[1]) + (red[2] + red[3])) + red[4];
}

// ---------------- K3: final deterministic reduction over 128 partials ----------------
__global__ __launch_bounds__(64) void k3_reduce(
    const float* __restrict__ partials, float* __restrict__ out)
{
  const int lane = threadIdx.x;
  float a = partials[lane] + partials[lane + 64];
  #pragma unroll
  for (int m = 32; m >= 1; m >>= 1) a += __shfl_xor(a, m);
  if (lane == 0) out[0] = a * (float)(1.0 / ((double)T_ * B_ * F_));
}

extern "C" void kernel_launch(void* const* d_in, const int* in_sizes, int n_in,
                              void* d_out, int out_size, void* d_ws, size_t ws_size,
                              hipStream_t stream) {
  const float* feats = (const float*)d_in[0];
  const float* e0    = (const float*)d_in[1];
  const float* W_ih  = (const float*)d_in[2];
  const float* W_hh  = (const float*)d_in[3];
  const float* b_ih  = (const float*)d_in[4];
  const float* b_hh  = (const float*)d_in[5];
  const float* W_dec = (const float*)d_in[6];
  const float* b_dec = (const float*)d_in[7];
  float* out = (float*)d_out;

  float* ws = (float*)d_ws;
  float* h_seq    = ws;                                    // B*T*HS_ floats (b-major, padded)
  float* xgates   = ws + (size_t)B_ * T_ * HS_;            // B*T*G floats (b-major)
  float* partials = xgates + (size_t)B_ * T_ * G_;         // 128 floats
  float* Wt       = partials + 128;                        // FP_*G_ floats

  hipLaunchKernelGGL(k1a_pool, dim3(T_ * (B_ / 8)), dim3(256), 0, stream,
                     feats, h_seq, W_ih, Wt);
  hipLaunchKernelGGL(k1b_gemm, dim3(B_ * 16), dim3(256), 0, stream,
                     h_seq, Wt, b_ih, xgates);
  hipLaunchKernelGGL(k2_fused, dim3(B_), dim3(320), 0, stream,
                     e0, W_hh, b_hh, xgates, h_seq, W_dec, b_dec, partials);
  hipLaunchKernelGGL(k3_reduce, dim3(1), dim3(64), 0, stream,
                     partials, out);
}